// Round 6
// baseline (285.776 us; speedup 1.0000x reference)
//
#include <hip/hip_runtime.h>
#include <hip/hip_bf16.h>

typedef unsigned short u16;
typedef __attribute__((ext_vector_type(8))) __bf16 bf16x8;
typedef __attribute__((ext_vector_type(4))) float floatx4;

#define B_   16
#define N1_  4096
#define N2_  1024
#define C1_  128
#define C2_  256
#define CIN_ 384
#define CM_  256
#define CO_  128

__device__ __forceinline__ u16 f2bf(float f) {
  unsigned u = __float_as_uint(f);
  u = (u + 0x7fffu + ((u >> 16) & 1u)) >> 16;
  return (u16)u;
}
__device__ __forceinline__ float bf2f(u16 h) {
  return __uint_as_float(((unsigned)h) << 16);
}

union U128 { uint4 u; bf16x8 v; u16 s[8]; };

__device__ __forceinline__ bf16x8 ldfrag(const u16* p) {
  U128 x; x.u = *(const uint4*)p; return x.v;
}
__device__ __forceinline__ uint4 pack8(const u16* h) {
  uint4 u;
  u.x = (unsigned)h[0] | ((unsigned)h[1] << 16);
  u.y = (unsigned)h[2] | ((unsigned)h[3] << 16);
  u.z = (unsigned)h[4] | ((unsigned)h[5] << 16);
  u.w = (unsigned)h[6] | ((unsigned)h[7] << 16);
  return u;
}

// Counted-vmcnt wait (T4): never drain to 0 in the main loop. "memory" clobber
// orders all memory ops across it; sched_barrier pins scheduling (rule #18).
#define WAITVM(N) do { asm volatile("s_waitcnt vmcnt(" #N ")" ::: "memory"); \
                       __builtin_amdgcn_sched_barrier(0); } while (0)

// Tiled operand layout (MFMA-fragment-major):
//   frag(tile, kt) at [tile][kt][lane][8] u16, lane = quad*16+col,
//   element j = M[row=col][k = kt*32 + quad*8 + j]. Wave frag load = base + lane*16B.

// ---------------- K1a: 3-NN partial (128-cand chunk, 1 pt/thread, if-chain insert)
//                  + castw side-job ----------------
__global__ __launch_bounds__(256) void knn_part_kernel(
    const float* __restrict__ xyz1, const float* __restrict__ xyz2,
    float* __restrict__ pd, int* __restrict__ pi,
    const float* __restrict__ w0, const float* __restrict__ w1,
    u16* __restrict__ w0b, u16* __restrict__ w1b)
{
  __shared__ float4 sp[128];
  int t = threadIdx.x;
  if (blockIdx.x == 16) {                          // ---- castw side-job ----
    int item = (blockIdx.y * 8 + blockIdx.z) * 256 + t;   // 0..32767
    if (item < 12288) {                             // w0: 256 rows x 48 chunks
      int m = item / 48, kc = item % 48;
      const float* p = w0 + m * CIN_ + kc * 8;
      u16 h8[8];
      #pragma unroll
      for (int j = 0; j < 8; ++j) h8[j] = f2bf(p[j]);
      int mt = m >> 4, col = m & 15, kt = kc >> 2, quad = kc & 3;
      *(uint4*)(w0b + ((mt*12 + kt)*512 + (quad*16 + col)*8)) = pack8(h8);
    } else if (item < 16384) {                      // w1: 128 rows x 32 chunks
      int i2 = item - 12288;
      int m = i2 >> 5, kc = i2 & 31;
      const float* p = w1 + m * CM_ + kc * 8;
      u16 h8[8];
      #pragma unroll
      for (int j = 0; j < 8; ++j) h8[j] = f2bf(p[j]);
      int mt = m >> 4, col = m & 15, kt = kc >> 2, quad = kc & 3;
      *(uint4*)(w1b + ((mt*8 + kt)*512 + (quad*16 + col)*8)) = pack8(h8);
    }
    return;
  }
  // ---- knn: one point/thread, 128 candidates ----
  int b = blockIdx.y, chunk = blockIdx.z;
  const float* p2 = xyz2 + ((size_t)b * N2_ + chunk * 128) * 3;
  if (t < 128) sp[t] = make_float4(p2[t*3], p2[t*3+1], p2[t*3+2], 0.f);
  __syncthreads();
  int i = blockIdx.x * 256 + t;
  const float* p1 = xyz1 + ((size_t)b * N1_ + i) * 3;
  float x = p1[0], y = p1[1], z = p1[2];
  float d0 = 1e30f, d1 = 1e30f, d2 = 1e30f;
  int i0 = 0, i1 = 0, i2 = 0;
  int jb = chunk * 128;
  #pragma unroll 4
  for (int j = 0; j < 128; ++j) {
    float4 p = sp[j];                              // broadcast: conflict-free
    float dx = x - p.x, dy = y - p.y, dz = z - p.z;
    float d = dx*dx + dy*dy + dz*dz;
    if (d < d2) {                                  // strict <: stable (earlier j wins ties)
      int jj = jb + j;
      if (d < d0)      { d2=d1; i2=i1; d1=d0; i1=i0; d0=d; i0=jj; }
      else if (d < d1) { d2=d1; i2=i1; d1=d;  i1=jj; }
      else             { d2=d;  i2=jj; }
    }
  }
  int o = chunk*65536 + b*4096 + i;
  pd[o] = d0; pd[o + 524288] = d1; pd[o + 1048576] = d2;
  pi[o] = i0; pi[o + 524288] = i1; pi[o + 1048576] = i2;
}

// ---------------- K1.5: fused (x<16: transpose feat2 | x>=16: knn merge) ----------------
__global__ __launch_bounds__(256) void tr2m_kernel(
    const float* __restrict__ feat2, u16* __restrict__ feat2Tb,
    const float* __restrict__ pd, const int* __restrict__ pi,
    int* __restrict__ idx_out, float* __restrict__ w_out)
{
  __shared__ float sA[64][257];
  int t = threadIdx.x;
  if (blockIdx.x >= 16) {
    // ---- knn merge side-job ----
    int p = (blockIdx.y * 16 + (blockIdx.x - 16)) * 256 + t;   // 0..65535
    float d0 = 1e30f, d1 = 1e30f, d2 = 1e30f;
    int i0 = 0, i1 = 0, i2 = 0;
    #pragma unroll
    for (int c = 0; c < 8; ++c) {                  // ascending-j chunk order: stable
      int o = c*65536 + p;
      #pragma unroll
      for (int k = 0; k < 3; ++k) {
        float d = pd[o + k*524288];
        int ix = pi[o + k*524288];
        bool c2 = d < d2, c1 = d < d1, c0 = d < d0;
        d2 = c1 ? d1 : (c2 ? d  : d2);
        i2 = c1 ? i1 : (c2 ? ix : i2);
        d1 = c0 ? d0 : (c1 ? d  : d1);
        i1 = c0 ? i0 : (c1 ? ix : i1);
        d0 = c0 ? d  : d0;
        i0 = c0 ? ix : i0;
      }
    }
    float w0 = 1.f/(d0+1e-8f), w1 = 1.f/(d1+1e-8f), w2 = 1.f/(d2+1e-8f);
    float inv = 1.f/(w0+w1+w2);
    idx_out[p]          = i0;
    idx_out[p +  65536] = i1;
    idx_out[p + 131072] = i2;
    w_out[p]            = w0*inv;
    w_out[p +  65536]   = w1*inv;
    w_out[p + 131072]   = w2*inv;
    return;
  }
  // ---- feat2 transpose ----
  int b = blockIdx.y;
  int n0 = blockIdx.x * 64;
  #pragma unroll
  for (int j = 0; j < 16; ++j) {
    int flat4 = t + j * 256;                       // 4096 float4s: 256c x 64n
    int c = flat4 >> 4, nn4 = (flat4 & 15) * 4;
    float4 v = *(const float4*)(feat2 + ((size_t)b*C2_ + c)*N2_ + n0 + nn4);
    sA[nn4+0][c] = v.x; sA[nn4+1][c] = v.y; sA[nn4+2][c] = v.z; sA[nn4+3][c] = v.w;
  }
  __syncthreads();
  int nn = t & 63, chunk = t >> 6;                 // 64 channels per thread
  u16* dst = feat2Tb + ((size_t)b*N2_ + n0 + nn)*C2_ + chunk*64;
  #pragma unroll
  for (int g = 0; g < 8; ++g) {
    u16 h8[8];
    #pragma unroll
    for (int j = 0; j < 8; ++j) h8[j] = f2bf(sA[nn][chunk*64 + g*8 + j]);
    *(uint4*)(dst + g*8) = pack8(h8);
  }
}

// ---------------- K2: fused prep (x<64: feat1 transpose | x>=64: 3NN interp) ----------------
__global__ __launch_bounds__(256) void prep_fused_kernel(
    const float* __restrict__ feat1, const u16* __restrict__ feat2Tb,
    const int* __restrict__ idx_in, const float* __restrict__ w_in,
    u16* __restrict__ xcatT)
{
  __shared__ float sA[64][133];
  int b = blockIdx.y;
  int t = threadIdx.x;
  if (blockIdx.x < 64) {
    // ---- feat1 transpose -> xcatT kt 0..3 ----
    int n0 = blockIdx.x * 64;
    #pragma unroll
    for (int j = 0; j < 8; ++j) {
      int flat4 = t + j * 256;                     // 2048 float4s: 128c x 64n
      int c = flat4 >> 4, nn4 = (flat4 & 15) * 4;
      float4 v = *(const float4*)(feat1 + ((size_t)b*C1_ + c)*N1_ + n0 + nn4);
      sA[nn4+0][c] = v.x; sA[nn4+1][c] = v.y; sA[nn4+2][c] = v.z; sA[nn4+3][c] = v.w;
    }
    __syncthreads();
    int nn = t & 63, chunk = t >> 6;
    int n = n0 + nn, nt = n >> 4, col = n & 15;
    u16* tb = xcatT + ((size_t)b*256 + nt)*12*512;
    #pragma unroll
    for (int g = 0; g < 4; ++g) {
      int c0 = chunk*32 + g*8;
      u16 h8[8];
      #pragma unroll
      for (int j = 0; j < 8; ++j) h8[j] = f2bf(sA[nn][c0 + j]);
      *(uint4*)(tb + (size_t)chunk*512 + (g*16 + col)*8) = pack8(h8);
    }
  } else {
    // ---- 3NN interpolate (bf16 gather) -> xcatT kt 4..11 ----
    int p0 = (blockIdx.x - 64) * 64;
    int seg = t & 31;                              // 8-channel segment
    int pl  = t >> 5;                              // 8 points per pass
    #pragma unroll 2
    for (int pass = 0; pass < 8; ++pass) {
      int n = p0 + pass*8 + pl;
      int base = b*N1_ + n;
      int i0 = idx_in[base], i1 = idx_in[base + 65536], i2 = idx_in[base + 131072];
      float w0 = w_in[base], w1 = w_in[base + 65536], w2 = w_in[base + 131072];
      const u16* fb = feat2Tb + (size_t)b*N2_*C2_ + seg*8;
      U128 a, c, d;
      a.u = *(const uint4*)(fb + (size_t)i0*C2_);
      c.u = *(const uint4*)(fb + (size_t)i1*C2_);
      d.u = *(const uint4*)(fb + (size_t)i2*C2_);
      u16 h8[8];
      #pragma unroll
      for (int j = 0; j < 8; ++j)
        h8[j] = f2bf(w0*bf2f(a.s[j]) + w1*bf2f(c.s[j]) + w2*bf2f(d.s[j]));
      int nt = n >> 4, col = n & 15;
      int kt = 4 + (seg >> 2), quad = seg & 3;
      *(uint4*)(xcatT + (((size_t)b*256 + nt)*12 + kt)*512 + (quad*16 + col)*8) = pack8(h8);
    }
  }
}

// ---------------- K3: GEMM1 MFMA, 1-wave blocks, 4-deep LDS ring, counted vmcnt ----------------
// grid (2,1024): x = M half (mb), y = global n-block (gnb = b*64 + nb).
// No __syncthreads in the loop (1 wave, no barrier): prefetch stage kt+3,
// s_waitcnt vmcnt(36) keeps 3 stages (36 loads) in flight across iterations.
__global__ __launch_bounds__(64) void gemm1_mfma(
    const u16* __restrict__ xcatT, const u16* __restrict__ w0b,
    const float* __restrict__ b0p, u16* __restrict__ y0T,
    float* __restrict__ p0)
{
  __shared__ u16 sbuf[4][12][512];                 // 48 KB ring: frag 0..7 = A mt, 8..11 = B nt
  int lane = threadIdx.x;
  int col = lane & 15, quad = lane >> 4;
  int mb = blockIdx.x;                             // 0..1
  int gnb = blockIdx.y;                            // 0..1023
  int b = gnb >> 6;
  int ntb4 = (gnb & 63) * 4;

  const u16* src[12];
  #pragma unroll
  for (int i = 0; i < 12; ++i)
    src[i] = (i < 8)
      ? (w0b + (size_t)((mb*8 + i) * 12) * 512 + lane*8)
      : (xcatT + (size_t)((b*256 + ntb4 + (i-8)) * 12) * 512 + lane*8);

  floatx4 acc[8][4] = {};

  // prologue: issue stages 0..2 (36 loads outstanding)
  #pragma unroll
  for (int s = 0; s < 3; ++s)
    #pragma unroll
    for (int i = 0; i < 12; ++i)
      __builtin_amdgcn_global_load_lds(
          (const __attribute__((address_space(1))) void*)(src[i] + (size_t)s*512),
          (__attribute__((address_space(3))) void*)(&sbuf[s][i][0]), 16, 0, 0);

  #pragma unroll 1
  for (int kt = 0; kt < 12; ++kt) {
    if (kt <= 8) {                                 // issue stage kt+3 into ring slot
      #pragma unroll
      for (int i = 0; i < 12; ++i)
        __builtin_amdgcn_global_load_lds(
            (const __attribute__((address_space(1))) void*)(src[i] + (size_t)(kt+3)*512),
            (__attribute__((address_space(3))) void*)(&sbuf[(kt+3)&3][i][0]), 16, 0, 0);
      WAITVM(36);                                  // stage kt resident; 3 stages in flight
    } else if (kt == 9)  { WAITVM(24); }
    else if (kt == 10)   { WAITVM(12); }
    else                 { WAITVM(0);  }
    const u16* cb = &sbuf[kt & 3][0][0];
    bf16x8 af[8], bfr[4];
    #pragma unroll
    for (int i = 0; i < 8; ++i) af[i] = ldfrag(cb + i*512 + lane*8);
    #pragma unroll
    for (int j = 0; j < 4; ++j) bfr[j] = ldfrag(cb + (8+j)*512 + lane*8);
    #pragma unroll
    for (int mt = 0; mt < 8; ++mt)
      #pragma unroll
      for (int nt = 0; nt < 4; ++nt)
        acc[mt][nt] = __builtin_amdgcn_mfma_f32_16x16x32_bf16(af[mt], bfr[nt], acc[mt][nt], 0, 0, 0);
  }

  int m0 = mb * 128;
  #pragma unroll
  for (int mt = 0; mt < 8; ++mt) {
    float4 bias4 = *(const float4*)(b0p + m0 + mt*16 + quad*4);
    float bia[4] = {bias4.x, bias4.y, bias4.z, bias4.w};
    int kt_out = mb*4 + (mt >> 1);
    int quad_out = ((mt & 1) << 1) | (quad >> 1);
    int j0 = (quad & 1) * 4;
    float s[4] = {}, q[4] = {};
    #pragma unroll
    for (int nt = 0; nt < 4; ++nt) {
      u16 h[4];
      #pragma unroll
      for (int r = 0; r < 4; ++r) {
        float v = acc[mt][nt][r] + bia[r];
        u16 hh = f2bf(v);
        float vr = bf2f(hh);
        h[r] = hh; s[r] += vr; q[r] += vr*vr;
      }
      *(ushort4*)(y0T + (((size_t)b*256 + ntb4 + nt)*8 + kt_out)*512 + (quad_out*16 + col)*8 + j0)
          = make_ushort4(h[0], h[1], h[2], h[3]);
    }
    #pragma unroll
    for (int r = 0; r < 4; ++r) {
      float ss = s[r], qq = q[r];
      #pragma unroll
      for (int msk = 1; msk < 16; msk <<= 1) { ss += __shfl_xor(ss, msk); qq += __shfl_xor(qq, msk); }
      if (col == 0)
        *(float2*)(p0 + ((size_t)(mb*128 + mt*16 + quad*4 + r) * 1024 + gnb) * 2)
            = make_float2(ss, qq);
    }
  }
}

// ---------------- K3.5: finalize stats (p[ch][1024][2]) -> scale/shift ----------------
__global__ __launch_bounds__(256) void stats_kernel(
    const float* __restrict__ p, const float* __restrict__ g,
    const float* __restrict__ be, float* __restrict__ scale,
    float* __restrict__ shift)
{
  int c = blockIdx.x, t = threadIdx.x;
  const float* base = p + (size_t)c * 2048;
  float s = 0.f, q = 0.f;
  #pragma unroll
  for (int i = 0; i < 4; ++i) {
    float2 v = *(const float2*)(base + (size_t)(t + i*256) * 2);
    s += v.x; q += v.y;
  }
  #pragma unroll
  for (int m = 1; m < 64; m <<= 1) { s += __shfl_xor(s, m); q += __shfl_xor(q, m); }
  __shared__ float2 red[4];
  if ((t & 63) == 0) red[t >> 6] = make_float2(s, q);
  __syncthreads();
  if (t == 0) {
    float ss = red[0].x + red[1].x + red[2].x + red[3].x;
    float qq = red[0].y + red[1].y + red[2].y + red[3].y;
    float mu  = ss * (1.f/65536.f);
    float var = qq * (1.f/65536.f) - mu*mu;
    float a = g[c] * rsqrtf(var + 1e-5f);
    scale[c] = a; shift[c] = be[c] - mu*a;
  }
}

// ---------------- K4: GEMM2 MFMA, 1-wave blocks, 4-deep ring, counted vmcnt,
//                  BN0+ReLU fused post-ds_read ----------------
// grid (1024): x = gnb. B (y0T) read exactly once chip-wide.
__global__ __launch_bounds__(64) void gemm2_mfma(
    const u16* __restrict__ y0T, const u16* __restrict__ w1b,
    const float* __restrict__ b1p,
    const float* __restrict__ scale0, const float* __restrict__ shift0,
    float* __restrict__ out, float* __restrict__ p1)
{
  __shared__ u16 sbuf[4][12][512];                 // 48 KB ring
  __shared__ float a0s[CM_], bb0s[CM_];
  int lane = threadIdx.x;
  int col = lane & 15, quad = lane >> 4;
  int gnb = blockIdx.x;
  int b = gnb >> 6;
  int ntb4 = (gnb & 63) * 4;

  *(float4*)&a0s[lane*4]  = *(const float4*)(scale0 + lane*4);
  *(float4*)&bb0s[lane*4] = *(const float4*)(shift0 + lane*4);

  const u16* src[12];
  #pragma unroll
  for (int i = 0; i < 12; ++i)
    src[i] = (i < 8)
      ? (w1b + (size_t)(i * 8) * 512 + lane*8)
      : (y0T + (size_t)((b*256 + ntb4 + (i-8)) * 8) * 512 + lane*8);

  floatx4 acc[8][4] = {};

  #pragma unroll
  for (int s = 0; s < 3; ++s)
    #pragma unroll
    for (int i = 0; i < 12; ++i)
      __builtin_amdgcn_global_load_lds(
          (const __attribute__((address_space(1))) void*)(src[i] + (size_t)s*512),
          (__attribute__((address_space(3))) void*)(&sbuf[s][i][0]), 16, 0, 0);
  // a0s/bb0s ds_writes done before any a0s read (lgkm drains; 1-wave so no barrier)
  asm volatile("s_waitcnt lgkmcnt(0)" ::: "memory");
  __builtin_amdgcn_sched_barrier(0);

  #pragma unroll 1
  for (int kt = 0; kt < 8; ++kt) {
    if (kt <= 4) {
      #pragma unroll
      for (int i = 0; i < 12; ++i)
        __builtin_amdgcn_global_load_lds(
            (const __attribute__((address_space(1))) void*)(src[i] + (size_t)(kt+3)*512),
            (__attribute__((address_space(3))) void*)(&sbuf[(kt+3)&3][i][0]), 16, 0, 0);
      WAITVM(36);
    } else if (kt == 5) { WAITVM(24); }
    else if (kt == 6)   { WAITVM(12); }
    else                { WAITVM(0);  }
    const u16* cb = &sbuf[kt & 3][0][0];
    bf16x8 af[8]; U128 braw[4];
    #pragma unroll
    for (int i = 0; i < 8; ++i) af[i] = ldfrag(cb + i*512 + lane*8);
    #pragma unroll
    for (int j = 0; j < 4; ++j) braw[j].u = *(const uint4*)(cb + (8+j)*512 + lane*8);
    int c0 = kt*32 + quad*8;                       // BN channels of these 8 elements
    float av[8], bv[8];
    *(float4*)&av[0] = *(const float4*)&a0s[c0];  *(float4*)&av[4] = *(const float4*)&a0s[c0+4];
    *(float4*)&bv[0] = *(const float4*)&bb0s[c0]; *(float4*)&bv[4] = *(const float4*)&bb0s[c0+4];
    bf16x8 bfv[4];
    #pragma unroll
    for (int j = 0; j < 4; ++j) {
      u16 h8[8];
      #pragma unroll
      for (int e = 0; e < 8; ++e)
        h8[e] = f2bf(fmaxf(fmaf(bf2f(braw[j].s[e]), av[e], bv[e]), 0.f));
      U128 x; x.u = pack8(h8); bfv[j] = x.v;
    }
    #pragma unroll
    for (int mt = 0; mt < 8; ++mt)
      #pragma unroll
      for (int nt = 0; nt < 4; ++nt)
        acc[mt][nt] = __builtin_amdgcn_mfma_f32_16x16x32_bf16(af[mt], bfv[nt], acc[mt][nt], 0, 0, 0);
  }

  #pragma unroll
  for (int mt = 0; mt < 8; ++mt) {
    float4 bias4 = *(const float4*)(b1p + mt*16 + quad*4);
    float bia[4] = {bias4.x, bias4.y, bias4.z, bias4.w};
    float s[4] = {}, q[4] = {};
    #pragma unroll
    for (int nt = 0; nt < 4; ++nt) {
      int n = ntb4*16 + nt*16 + col;
      #pragma unroll
      for (int r = 0; r < 4; ++r) {
        float v = acc[mt][nt][r] + bia[r];
        out[((size_t)b*CO_ + mt*16 + quad*4 + r)*N1_ + n] = v;
        s[r] += v; q[r] += v*v;
      }
    }
    #pragma unroll
    for (int r = 0; r < 4; ++r) {
      float ss = s[r], qq = q[r];
      #pragma unroll
      for (int msk = 1; msk < 16; msk <<= 1) { ss += __shfl_xor(ss, msk); qq += __shfl_xor(qq, msk); }
      if (col == 0)
        *(float2*)(p1 + ((size_t)(mt*16 + quad*4 + r) * 1024 + gnb) * 2)
            = make_float2(ss, qq);
    }
  }
}

// ---------------- K5: BN1 + ReLU in place on d_out ----------------
__global__ __launch_bounds__(256) void bnrelu_kernel(
    float* __restrict__ out, const float* __restrict__ scale1, const float* __restrict__ shift1)
{
  int idx = blockIdx.x * 256 + threadIdx.x;   // float4 index
  int c = (idx >> 10) & (CO_ - 1);
  float a = scale1[c];
  float bb = shift1[c];
  float4 v = ((const float4*)out)[idx];
  v.x = fmaxf(fmaf(v.x, a, bb), 0.f);
  v.y = fmaxf(fmaf(v.y, a, bb), 0.f);
  v.z = fmaxf(fmaf(v.z, a, bb), 0.f);
  v.w = fmaxf(fmaf(v.w, a, bb), 0.f);
  ((float4*)out)[idx] = v;
}

extern "C" void kernel_launch(void* const* d_in, const int* in_sizes, int n_in,
                              void* d_out, int out_size, void* d_ws, size_t ws_size,
                              hipStream_t stream)
{
  const float* xyz1  = (const float*)d_in[0];
  const float* xyz2  = (const float*)d_in[1];
  const float* feat1 = (const float*)d_in[2];
  const float* feat2 = (const float*)d_in[3];
  const float* w0    = (const float*)d_in[4];
  const float* b0    = (const float*)d_in[5];
  const float* g0    = (const float*)d_in[6];
  const float* be0   = (const float*)d_in[7];
  const float* w1    = (const float*)d_in[8];
  const float* b1    = (const float*)d_in[9];
  const float* g1    = (const float*)d_in[10];
  const float* be1   = (const float*)d_in[11];
  float* out = (float*)d_out;
  char* ws = (char*)d_ws;

  // workspace layout (bytes)
  u16*   xcatT   = (u16*)ws;                                   // 50331648
  float* knn_pd  = (float*)ws;                                 // 6291456 (alias xcatT; dead before prep)
  float* p1      = (float*)ws;                                 // 1048576 (alias xcatT; gemm2 writes after gemm1 consumed xcatT)
  int*   knn_pi  = (int*)(ws + 6291456);                       // 6291456
  u16*   y0T     = (u16*)(ws + 50331648);                      // 33554432
  u16*   feat2Tb = (u16*)(ws + 50331648);                      // 8 MB (alias y0T, dead before gemm1)
  u16*   w0b     = (u16*)(ws + 83886080);                      // 196608
  u16*   w1b     = (u16*)(ws + 84082688);                      // 65536
  int*   idx_buf = (int*)(ws + 84148224);                      // 786432
  float* w_buf   = (float*)(ws + 84934656);                    // 786432
  float* p0      = (float*)(ws + 84148224);                    // 2097152 (alias idx_buf+w_buf; dead after prep)
  float* scale0  = (float*)(ws + 87293952);                    // 256
  float* shift0  = scale0 + 256;
  float* scale1  = scale0 + 512;
  float* shift1  = scale0 + 640;

  knn_part_kernel <<<dim3(17,16,8),   256, 0, stream>>>(xyz1, xyz2, knn_pd, knn_pi, w0, w1, w0b, w1b);
  tr2m_kernel     <<<dim3(32,16),     256, 0, stream>>>(feat2, feat2Tb, knn_pd, knn_pi, idx_buf, w_buf);
  prep_fused_kernel<<<dim3(128,16),   256, 0, stream>>>(feat1, feat2Tb, idx_buf, w_buf, xcatT);
  gemm1_mfma      <<<dim3(2,1024),     64, 0, stream>>>(xcatT, w0b, b0, y0T, p0);
  stats_kernel    <<<256,             256, 0, stream>>>(p0, g0, be0, scale0, shift0);
  gemm2_mfma      <<<1024,             64, 0, stream>>>(y0T, w1b, b1, scale0, shift0, out, p1);
  stats_kernel    <<<128,             256, 0, stream>>>(p1, g1, be1, scale1, shift1);
  bnrelu_kernel   <<<8192,            256, 0, stream>>>(out, scale1, shift1);
}

// Round 7
// 251.953 us; speedup vs baseline: 1.1342x; 1.1342x over previous
//
#include <hip/hip_runtime.h>
#include <hip/hip_bf16.h>

typedef unsigned short u16;
typedef __attribute__((ext_vector_type(8))) __bf16 bf16x8;
typedef __attribute__((ext_vector_type(4))) float floatx4;

#define B_   16
#define N1_  4096
#define N2_  1024
#define C1_  128
#define C2_  256
#define CIN_ 384
#define CM_  256
#define CO_  128

__device__ __forceinline__ u16 f2bf(float f) {
  unsigned u = __float_as_uint(f);
  u = (u + 0x7fffu + ((u >> 16) & 1u)) >> 16;
  return (u16)u;
}
__device__ __forceinline__ float bf2f(u16 h) {
  return __uint_as_float(((unsigned)h) << 16);
}

union U128 { uint4 u; bf16x8 v; u16 s[8]; };

__device__ __forceinline__ bf16x8 ldfrag(const u16* p) {
  U128 x; x.u = *(const uint4*)p; return x.v;
}
__device__ __forceinline__ uint4 pack8(const u16* h) {
  uint4 u;
  u.x = (unsigned)h[0] | ((unsigned)h[1] << 16);
  u.y = (unsigned)h[2] | ((unsigned)h[3] << 16);
  u.z = (unsigned)h[4] | ((unsigned)h[5] << 16);
  u.w = (unsigned)h[6] | ((unsigned)h[7] << 16);
  return u;
}

// Tiled operand layout (MFMA-fragment-major):
//   frag(tile, kt) at [tile][kt][lane][8] u16, lane = quad*16+col,
//   element j = M[row=col][k = kt*32 + quad*8 + j]. Wave frag load = base + lane*16B.
// GEMM staging lesson (R5/R6): global_load_lds deep rings stall at the LDS-DMA
// queue (R6: 4-deep ring = 2x SLOWER); register staging with compiler-counted
// vmcnt is the path -- each lane's 16B global load IS its fragment.

// ---------------- K1a: 3-NN partial (128-cand chunk, 1 pt/thread, if-chain insert)
//                  + castw side-job ----------------
__global__ __launch_bounds__(256) void knn_part_kernel(
    const float* __restrict__ xyz1, const float* __restrict__ xyz2,
    float* __restrict__ pd, int* __restrict__ pi,
    const float* __restrict__ w0, const float* __restrict__ w1,
    u16* __restrict__ w0b, u16* __restrict__ w1b)
{
  __shared__ float4 sp[128];
  int t = threadIdx.x;
  if (blockIdx.x == 16) {                          // ---- castw side-job ----
    int item = (blockIdx.y * 8 + blockIdx.z) * 256 + t;   // 0..32767
    if (item < 12288) {                             // w0: 256 rows x 48 chunks
      int m = item / 48, kc = item % 48;
      const float* p = w0 + m * CIN_ + kc * 8;
      u16 h8[8];
      #pragma unroll
      for (int j = 0; j < 8; ++j) h8[j] = f2bf(p[j]);
      int mt = m >> 4, col = m & 15, kt = kc >> 2, quad = kc & 3;
      *(uint4*)(w0b + ((mt*12 + kt)*512 + (quad*16 + col)*8)) = pack8(h8);
    } else if (item < 16384) {                      // w1: 128 rows x 32 chunks
      int i2 = item - 12288;
      int m = i2 >> 5, kc = i2 & 31;
      const float* p = w1 + m * CM_ + kc * 8;
      u16 h8[8];
      #pragma unroll
      for (int j = 0; j < 8; ++j) h8[j] = f2bf(p[j]);
      int mt = m >> 4, col = m & 15, kt = kc >> 2, quad = kc & 3;
      *(uint4*)(w1b + ((mt*8 + kt)*512 + (quad*16 + col)*8)) = pack8(h8);
    }
    return;
  }
  // ---- knn: one point/thread, 128 candidates ----
  int b = blockIdx.y, chunk = blockIdx.z;
  const float* p2 = xyz2 + ((size_t)b * N2_ + chunk * 128) * 3;
  if (t < 128) sp[t] = make_float4(p2[t*3], p2[t*3+1], p2[t*3+2], 0.f);
  __syncthreads();
  int i = blockIdx.x * 256 + t;
  const float* p1 = xyz1 + ((size_t)b * N1_ + i) * 3;
  float x = p1[0], y = p1[1], z = p1[2];
  float d0 = 1e30f, d1 = 1e30f, d2 = 1e30f;
  int i0 = 0, i1 = 0, i2 = 0;
  int jb = chunk * 128;
  #pragma unroll 4
  for (int j = 0; j < 128; ++j) {
    float4 p = sp[j];                              // broadcast: conflict-free
    float dx = x - p.x, dy = y - p.y, dz = z - p.z;
    float d = dx*dx + dy*dy + dz*dz;
    if (d < d2) {                                  // strict <: stable (earlier j wins ties)
      int jj = jb + j;
      if (d < d0)      { d2=d1; i2=i1; d1=d0; i1=i0; d0=d; i0=jj; }
      else if (d < d1) { d2=d1; i2=i1; d1=d;  i1=jj; }
      else             { d2=d;  i2=jj; }
    }
  }
  int o = chunk*65536 + b*4096 + i;
  pd[o] = d0; pd[o + 524288] = d1; pd[o + 1048576] = d2;
  pi[o] = i0; pi[o + 524288] = i1; pi[o + 1048576] = i2;
}

// ---------------- K1.5: fused (x<16: transpose feat2 | x>=16: knn merge) ----------------
__global__ __launch_bounds__(256) void tr2m_kernel(
    const float* __restrict__ feat2, u16* __restrict__ feat2Tb,
    const float* __restrict__ pd, const int* __restrict__ pi,
    int* __restrict__ idx_out, float* __restrict__ w_out)
{
  __shared__ float sA[64][257];
  int t = threadIdx.x;
  if (blockIdx.x >= 16) {
    // ---- knn merge side-job ----
    int p = (blockIdx.y * 16 + (blockIdx.x - 16)) * 256 + t;   // 0..65535
    float d0 = 1e30f, d1 = 1e30f, d2 = 1e30f;
    int i0 = 0, i1 = 0, i2 = 0;
    #pragma unroll
    for (int c = 0; c < 8; ++c) {                  // ascending-j chunk order: stable
      int o = c*65536 + p;
      #pragma unroll
      for (int k = 0; k < 3; ++k) {
        float d = pd[o + k*524288];
        int ix = pi[o + k*524288];
        bool c2 = d < d2, c1 = d < d1, c0 = d < d0;
        d2 = c1 ? d1 : (c2 ? d  : d2);
        i2 = c1 ? i1 : (c2 ? ix : i2);
        d1 = c0 ? d0 : (c1 ? d  : d1);
        i1 = c0 ? i0 : (c1 ? ix : i1);
        d0 = c0 ? d  : d0;
        i0 = c0 ? ix : i0;
      }
    }
    float w0 = 1.f/(d0+1e-8f), w1 = 1.f/(d1+1e-8f), w2 = 1.f/(d2+1e-8f);
    float inv = 1.f/(w0+w1+w2);
    idx_out[p]          = i0;
    idx_out[p +  65536] = i1;
    idx_out[p + 131072] = i2;
    w_out[p]            = w0*inv;
    w_out[p +  65536]   = w1*inv;
    w_out[p + 131072]   = w2*inv;
    return;
  }
  // ---- feat2 transpose ----
  int b = blockIdx.y;
  int n0 = blockIdx.x * 64;
  #pragma unroll
  for (int j = 0; j < 16; ++j) {
    int flat4 = t + j * 256;                       // 4096 float4s: 256c x 64n
    int c = flat4 >> 4, nn4 = (flat4 & 15) * 4;
    float4 v = *(const float4*)(feat2 + ((size_t)b*C2_ + c)*N2_ + n0 + nn4);
    sA[nn4+0][c] = v.x; sA[nn4+1][c] = v.y; sA[nn4+2][c] = v.z; sA[nn4+3][c] = v.w;
  }
  __syncthreads();
  int nn = t & 63, chunk = t >> 6;                 // 64 channels per thread
  u16* dst = feat2Tb + ((size_t)b*N2_ + n0 + nn)*C2_ + chunk*64;
  #pragma unroll
  for (int g = 0; g < 8; ++g) {
    u16 h8[8];
    #pragma unroll
    for (int j = 0; j < 8; ++j) h8[j] = f2bf(sA[nn][chunk*64 + g*8 + j]);
    *(uint4*)(dst + g*8) = pack8(h8);
  }
}

// ---------------- K2: fused prep (x<64: feat1 transpose | x>=64: 3NN interp) ----------------
__global__ __launch_bounds__(256) void prep_fused_kernel(
    const float* __restrict__ feat1, const u16* __restrict__ feat2Tb,
    const int* __restrict__ idx_in, const float* __restrict__ w_in,
    u16* __restrict__ xcatT)
{
  __shared__ float sA[64][133];
  int b = blockIdx.y;
  int t = threadIdx.x;
  if (blockIdx.x < 64) {
    // ---- feat1 transpose -> xcatT kt 0..3 ----
    int n0 = blockIdx.x * 64;
    #pragma unroll
    for (int j = 0; j < 8; ++j) {
      int flat4 = t + j * 256;                     // 2048 float4s: 128c x 64n
      int c = flat4 >> 4, nn4 = (flat4 & 15) * 4;
      float4 v = *(const float4*)(feat1 + ((size_t)b*C1_ + c)*N1_ + n0 + nn4);
      sA[nn4+0][c] = v.x; sA[nn4+1][c] = v.y; sA[nn4+2][c] = v.z; sA[nn4+3][c] = v.w;
    }
    __syncthreads();
    int nn = t & 63, chunk = t >> 6;
    int n = n0 + nn, nt = n >> 4, col = n & 15;
    u16* tb = xcatT + ((size_t)b*256 + nt)*12*512;
    #pragma unroll
    for (int g = 0; g < 4; ++g) {
      int c0 = chunk*32 + g*8;
      u16 h8[8];
      #pragma unroll
      for (int j = 0; j < 8; ++j) h8[j] = f2bf(sA[nn][c0 + j]);
      *(uint4*)(tb + (size_t)chunk*512 + (g*16 + col)*8) = pack8(h8);
    }
  } else {
    // ---- 3NN interpolate (bf16 gather) -> xcatT kt 4..11 ----
    int p0 = (blockIdx.x - 64) * 64;
    int seg = t & 31;                              // 8-channel segment
    int pl  = t >> 5;                              // 8 points per pass
    #pragma unroll 2
    for (int pass = 0; pass < 8; ++pass) {
      int n = p0 + pass*8 + pl;
      int base = b*N1_ + n;
      int i0 = idx_in[base], i1 = idx_in[base + 65536], i2 = idx_in[base + 131072];
      float w0 = w_in[base], w1 = w_in[base + 65536], w2 = w_in[base + 131072];
      const u16* fb = feat2Tb + (size_t)b*N2_*C2_ + seg*8;
      U128 a, c, d;
      a.u = *(const uint4*)(fb + (size_t)i0*C2_);
      c.u = *(const uint4*)(fb + (size_t)i1*C2_);
      d.u = *(const uint4*)(fb + (size_t)i2*C2_);
      u16 h8[8];
      #pragma unroll
      for (int j = 0; j < 8; ++j)
        h8[j] = f2bf(w0*bf2f(a.s[j]) + w1*bf2f(c.s[j]) + w2*bf2f(d.s[j]));
      int nt = n >> 4, col = n & 15;
      int kt = 4 + (seg >> 2), quad = seg & 3;
      *(uint4*)(xcatT + (((size_t)b*256 + nt)*12 + kt)*512 + (quad*16 + col)*8) = pack8(h8);
    }
  }
}

// ---------------- K3: GEMM1 MFMA, register-staged period-3 depth-2 pipeline ----------------
// grid (32,16,2): x = 8-ntile block, y = batch, z = M half. 4 waves (2x2), wave
// tile 64x64. Each lane's 16B global load IS its fragment (fragment-major layout);
// compute kt from buf kt%3, then restage kt+3 into it -> stages kt+1,kt+2 always
// in flight; compiler inserts counted vmcnt(16) before each MM (no drain-to-0).
__global__ __launch_bounds__(256) void gemm1_mfma(
    const u16* __restrict__ xcatT, const u16* __restrict__ w0b,
    const float* __restrict__ b0p, u16* __restrict__ y0T,
    float* __restrict__ p0)
{
  __shared__ float ps[4][64][2];                   // [wave][ch64][sum|sq]
  int t = threadIdx.x;
  int wave = t >> 6, lane = t & 63;
  int col = lane & 15, quad = lane >> 4;
  int wm = wave >> 1, wn = wave & 1;
  int b = blockIdx.y;
  int mtb = blockIdx.z*8 + wm*4;
  int ntb = blockIdx.x*8 + wn*4;

  const u16* ap = w0b + lane*8;
  const u16* bp = xcatT + ((size_t)(b*256 + ntb)*12)*512 + lane*8;

  floatx4 acc[4][4] = {};
  bf16x8 aA[4], aB[4], aC[4], bA[4], bB[4], bC[4];

#define G1_LDA(BUF, KT) { _Pragma("unroll") for (int i = 0; i < 4; ++i) \
    BUF[i] = ldfrag(ap + (size_t)((mtb+i)*12 + (KT))*512); }
#define G1_LDB(BUF, KT) { _Pragma("unroll") for (int i = 0; i < 4; ++i) \
    BUF[i] = ldfrag(bp + (size_t)(i*12 + (KT))*512); }
#define G1_MM(A_, B_) { _Pragma("unroll") for (int mt = 0; mt < 4; ++mt) \
    _Pragma("unroll") for (int nt = 0; nt < 4; ++nt) \
      acc[mt][nt] = __builtin_amdgcn_mfma_f32_16x16x32_bf16(A_[mt], B_[nt], acc[mt][nt], 0, 0, 0); }

  G1_LDA(aA,0);  G1_LDB(bA,0);
  G1_LDA(aB,1);  G1_LDB(bB,1);
  G1_LDA(aC,2);  G1_LDB(bC,2);
  G1_MM(aA,bA);  G1_LDA(aA,3);  G1_LDB(bA,3);
  G1_MM(aB,bB);  G1_LDA(aB,4);  G1_LDB(bB,4);
  G1_MM(aC,bC);  G1_LDA(aC,5);  G1_LDB(bC,5);
  G1_MM(aA,bA);  G1_LDA(aA,6);  G1_LDB(bA,6);
  G1_MM(aB,bB);  G1_LDA(aB,7);  G1_LDB(bB,7);
  G1_MM(aC,bC);  G1_LDA(aC,8);  G1_LDB(bC,8);
  G1_MM(aA,bA);  G1_LDA(aA,9);  G1_LDB(bA,9);
  G1_MM(aB,bB);  G1_LDA(aB,10); G1_LDB(bB,10);
  G1_MM(aC,bC);  G1_LDA(aC,11); G1_LDB(bC,11);
  G1_MM(aA,bA);
  G1_MM(aB,bB);
  G1_MM(aC,bC);

  int m0 = blockIdx.z*128 + wm*64;
  #pragma unroll
  for (int mt = 0; mt < 4; ++mt) {
    float4 bias4 = *(const float4*)(b0p + m0 + mt*16 + quad*4);
    float bia[4] = {bias4.x, bias4.y, bias4.z, bias4.w};
    int kt_out = (m0 >> 5) + (mt >> 1);
    int quad_out = ((mt & 1) << 1) | (quad >> 1);
    int j0 = (quad & 1) * 4;
    float s[4] = {}, q[4] = {};
    #pragma unroll
    for (int nt = 0; nt < 4; ++nt) {
      int nt_g = ntb + nt;
      u16 h[4];
      #pragma unroll
      for (int r = 0; r < 4; ++r) {
        float v = acc[mt][nt][r] + bia[r];
        u16 hh = f2bf(v);
        float vr = bf2f(hh);
        h[r] = hh; s[r] += vr; q[r] += vr*vr;
      }
      *(ushort4*)(y0T + (((size_t)b*256 + nt_g)*8 + kt_out)*512 + (quad_out*16 + col)*8 + j0)
          = make_ushort4(h[0], h[1], h[2], h[3]);
    }
    #pragma unroll
    for (int r = 0; r < 4; ++r) {
      float ss = s[r], qq = q[r];
      #pragma unroll
      for (int msk = 1; msk < 16; msk <<= 1) { ss += __shfl_xor(ss, msk); qq += __shfl_xor(qq, msk); }
      if (col == 0) {
        ps[wave][mt*16 + quad*4 + r][0] = ss;
        ps[wave][mt*16 + quad*4 + r][1] = qq;
      }
    }
  }
  __syncthreads();
  {
    int c = t >> 1, k = t & 1;                     // c in [0,128)
    int wbase = (c >> 6) * 2, ch = c & 63;
    float v = ps[wbase][ch][k] + ps[wbase+1][ch][k];
    size_t l = (size_t)blockIdx.z*512 + blockIdx.y*32 + blockIdx.x;
    p0[l*256 + t] = v;
  }
}

// ---------------- K3.5: finalize stats -> scale/shift per channel ----------------
__global__ __launch_bounds__(256) void stats_kernel(
    const float* __restrict__ p, const float* __restrict__ g,
    const float* __restrict__ be, float* __restrict__ scale,
    float* __restrict__ shift, int half_split, int nl)
{
  int c = blockIdx.x, t = threadIdx.x;
  size_t base = half_split ? ((size_t)(c >> 7) * 512 * 256 + (size_t)(c & 127) * 2)
                           : ((size_t)c * 2);
  float s = 0.f, q = 0.f;
  for (int i = 0; i < nl; ++i) {
    float2 v = *(const float2*)(p + base + (size_t)(t + i*256) * 256);
    s += v.x; q += v.y;
  }
  #pragma unroll
  for (int m = 1; m < 64; m <<= 1) { s += __shfl_xor(s, m); q += __shfl_xor(q, m); }
  __shared__ float2 red[4];
  if ((t & 63) == 0) red[t >> 6] = make_float2(s, q);
  __syncthreads();
  if (t == 0) {
    float ss = red[0].x + red[1].x + red[2].x + red[3].x;
    float qq = red[0].y + red[1].y + red[2].y + red[3].y;
    float mu  = ss * (1.f/65536.f);
    float var = qq * (1.f/65536.f) - mu*mu;
    float a = g[c] * rsqrtf(var + 1e-5f);
    scale[c] = a; shift[c] = be[c] - mu*a;
  }
}

// ---------------- K4: GEMM2 MFMA, register-staged period-3 depth-2, BN0+ReLU on B ----------------
// grid (32,16): 4 waves (2x2), wave tile 64x64, K=8 steps.
__global__ __launch_bounds__(256) void gemm2_mfma(
    const u16* __restrict__ y0T, const u16* __restrict__ w1b,
    const float* __restrict__ b1p,
    const float* __restrict__ scale0, const float* __restrict__ shift0,
    float* __restrict__ out, float* __restrict__ p1)
{
  __shared__ float a0s[CM_], bb0s[CM_];
  __shared__ float ps[4][64][2];
  int t = threadIdx.x;
  a0s[t] = scale0[t]; bb0s[t] = shift0[t];
  __syncthreads();
  int wave = t >> 6, lane = t & 63;
  int col = lane & 15, quad = lane >> 4;
  int wm = wave >> 1, wn = wave & 1;
  int b = blockIdx.y;
  int mtb = wm*4;
  int ntb = blockIdx.x*8 + wn*4;

  const u16* ap = w1b + lane*8;
  const u16* bp = y0T + ((size_t)(b*256 + ntb)*8)*512 + lane*8;

  floatx4 acc[4][4] = {};
  bf16x8 aA[4], aB[4], aC[4];
  U128 rA[4], rB[4], rC[4];

#define G2_LDA(BUF, KT) { _Pragma("unroll") for (int i = 0; i < 4; ++i) \
    BUF[i] = ldfrag(ap + (size_t)((mtb+i)*8 + (KT))*512); }
#define G2_LDB(BUF, KT) { _Pragma("unroll") for (int i = 0; i < 4; ++i) \
    BUF[i].u = *(const uint4*)(bp + (size_t)(i*8 + (KT))*512); }
#define G2_BNMM(A_, R_, KT) { \
    int c0 = (KT)*32 + quad*8; \
    float av[8], bv[8]; \
    *(float4*)&av[0] = *(const float4*)&a0s[c0];  *(float4*)&av[4] = *(const float4*)&a0s[c0+4]; \
    *(float4*)&bv[0] = *(const float4*)&bb0s[c0]; *(float4*)&bv[4] = *(const float4*)&bb0s[c0+4]; \
    bf16x8 bfv[4]; \
    _Pragma("unroll") for (int j = 0; j < 4; ++j) { \
      u16 h8[8]; \
      _Pragma("unroll") for (int e = 0; e < 8; ++e) \
        h8[e] = f2bf(fmaxf(fmaf(bf2f(R_[j].s[e]), av[e], bv[e]), 0.f)); \
      U128 x_; x_.u = pack8(h8); bfv[j] = x_.v; } \
    _Pragma("unroll") for (int mt = 0; mt < 4; ++mt) \
    _Pragma("unroll") for (int nt = 0; nt < 4; ++nt) \
      acc[mt][nt] = __builtin_amdgcn_mfma_f32_16x16x32_bf16(A_[mt], bfv[nt], acc[mt][nt], 0, 0, 0); }

  G2_LDA(aA,0);  G2_LDB(rA,0);
  G2_LDA(aB,1);  G2_LDB(rB,1);
  G2_LDA(aC,2);  G2_LDB(rC,2);
  G2_BNMM(aA,rA,0);  G2_LDA(aA,3);  G2_LDB(rA,3);
  G2_BNMM(aB,rB,1);  G2_LDA(aB,4);  G2_LDB(rB,4);
  G2_BNMM(aC,rC,2);  G2_LDA(aC,5);  G2_LDB(rC,5);
  G2_BNMM(aA,rA,3);  G2_LDA(aA,6);  G2_LDB(rA,6);
  G2_BNMM(aB,rB,4);  G2_LDA(aB,7);  G2_LDB(rB,7);
  G2_BNMM(aC,rC,5);
  G2_BNMM(aA,rA,6);
  G2_BNMM(aB,rB,7);

  int m0 = wm*64;
  int n0 = blockIdx.x*128 + wn*64;
  #pragma unroll
  for (int mt = 0; mt < 4; ++mt) {
    float4 bias4 = *(const float4*)(b1p + m0 + mt*16 + quad*4);
    float bia[4] = {bias4.x, bias4.y, bias4.z, bias4.w};
    float s[4] = {}, q[4] = {};
    #pragma unroll
    for (int nt = 0; nt < 4; ++nt) {
      int n = n0 + nt*16 + col;
      #pragma unroll
      for (int r = 0; r < 4; ++r) {
        float v = acc[mt][nt][r] + bia[r];
        out[((size_t)b*CO_ + m0 + mt*16 + quad*4 + r)*N1_ + n] = v;
        s[r] += v; q[r] += v*v;
      }
    }
    #pragma unroll
    for (int r = 0; r < 4; ++r) {
      float ss = s[r], qq = q[r];
      #pragma unroll
      for (int msk = 1; msk < 16; msk <<= 1) { ss += __shfl_xor(ss, msk); qq += __shfl_xor(qq, msk); }
      if (col == 0) {
        ps[wave][mt*16 + quad*4 + r][0] = ss;
        ps[wave][mt*16 + quad*4 + r][1] = qq;
      }
    }
  }
  __syncthreads();
  {
    int c = t >> 1, k = t & 1;
    int wbase = (c >> 6) * 2, ch = c & 63;
    float v = ps[wbase][ch][k] + ps[wbase+1][ch][k];
    size_t l = (size_t)blockIdx.y*32 + blockIdx.x;
    p1[l*256 + t] = v;
  }
}

// ---------------- K5: BN1 + ReLU in place on d_out ----------------
__global__ __launch_bounds__(256) void bnrelu_kernel(
    float* __restrict__ out, const float* __restrict__ scale1, const float* __restrict__ shift1)
{
  int idx = blockIdx.x * 256 + threadIdx.x;   // float4 index
  int c = (idx >> 10) & (CO_ - 1);
  float a = scale1[c];
  float bb = shift1[c];
  float4 v = ((const float4*)out)[idx];
  v.x = fmaxf(fmaf(v.x, a, bb), 0.f);
  v.y = fmaxf(fmaf(v.y, a, bb), 0.f);
  v.z = fmaxf(fmaf(v.z, a, bb), 0.f);
  v.w = fmaxf(fmaf(v.w, a, bb), 0.f);
  ((float4*)out)[idx] = v;
}

extern "C" void kernel_launch(void* const* d_in, const int* in_sizes, int n_in,
                              void* d_out, int out_size, void* d_ws, size_t ws_size,
                              hipStream_t stream)
{
  const float* xyz1  = (const float*)d_in[0];
  const float* xyz2  = (const float*)d_in[1];
  const float* feat1 = (const float*)d_in[2];
  const float* feat2 = (const float*)d_in[3];
  const float* w0    = (const float*)d_in[4];
  const float* b0    = (const float*)d_in[5];
  const float* g0    = (const float*)d_in[6];
  const float* be0   = (const float*)d_in[7];
  const float* w1    = (const float*)d_in[8];
  const float* b1    = (const float*)d_in[9];
  const float* g1    = (const float*)d_in[10];
  const float* be1   = (const float*)d_in[11];
  float* out = (float*)d_out;
  char* ws = (char*)d_ws;

  // workspace layout (bytes)
  u16*   xcatT   = (u16*)ws;                                   // 50331648
  float* knn_pd  = (float*)ws;                                 // 6291456 (alias xcatT; dead before prep)
  float* p1      = (float*)ws;                                 // 524288 (alias xcatT; gemm2 writes after gemm1 consumed xcatT)
  int*   knn_pi  = (int*)(ws + 6291456);                       // 6291456
  u16*   y0T     = (u16*)(ws + 50331648);                      // 33554432
  u16*   feat2Tb = (u16*)(ws + 50331648);                      // 8 MB (alias y0T, dead before gemm1)
  u16*   w0b     = (u16*)(ws + 83886080);                      // 196608
  u16*   w1b     = (u16*)(ws + 84082688);                      // 65536
  int*   idx_buf = (int*)(ws + 84148224);                      // 786432
  float* w_buf   = (float*)(ws + 84934656);                    // 786432
  float* p0      = (float*)(ws + 85721088);                    // 1048576
  float* scale0  = (float*)(ws + 87293952);                    // 256
  float* shift0  = scale0 + 256;
  float* scale1  = scale0 + 512;
  float* shift1  = scale0 + 640;

  knn_part_kernel <<<dim3(17,16,8),   256, 0, stream>>>(xyz1, xyz2, knn_pd, knn_pi, w0, w1, w0b, w1b);
  tr2m_kernel     <<<dim3(32,16),     256, 0, stream>>>(feat2, feat2Tb, knn_pd, knn_pi, idx_buf, w_buf);
  prep_fused_kernel<<<dim3(128,16),   256, 0, stream>>>(feat1, feat2Tb, idx_buf, w_buf, xcatT);
  gemm1_mfma      <<<dim3(32,16,2),   256, 0, stream>>>(xcatT, w0b, b0, y0T, p0);
  stats_kernel    <<<256,             256, 0, stream>>>(p0, g0, be0, scale0, shift0, 1, 2);
  gemm2_mfma      <<<dim3(32,16),     256, 0, stream>>>(y0T, w1b, b1, scale0, shift0, out, p1);
  stats_kernel    <<<128,             256, 0, stream>>>(p1, g1, be1, scale1, shift1, 0, 2);
  bnrelu_kernel   <<<8192,            256, 0, stream>>>(out, scale1, shift1);
}

// Round 8
// 248.150 us; speedup vs baseline: 1.1516x; 1.0153x over previous
//
#include <hip/hip_runtime.h>
#include <hip/hip_bf16.h>

typedef unsigned short u16;
typedef __attribute__((ext_vector_type(8))) __bf16 bf16x8;
typedef __attribute__((ext_vector_type(4))) float floatx4;

#define B_   16
#define N1_  4096
#define N2_  1024
#define C1_  128
#define C2_  256
#define CIN_ 384
#define CM_  256
#define CO_  128

__device__ __forceinline__ u16 f2bf(float f) {
  unsigned u = __float_as_uint(f);
  u = (u + 0x7fffu + ((u >> 16) & 1u)) >> 16;
  return (u16)u;
}
__device__ __forceinline__ float bf2f(u16 h) {
  return __uint_as_float(((unsigned)h) << 16);
}

union U128 { uint4 u; bf16x8 v; u16 s[8]; };

__device__ __forceinline__ bf16x8 ldfrag(const u16* p) {
  U128 x; x.u = *(const uint4*)p; return x.v;
}
__device__ __forceinline__ uint4 pack8(const u16* h) {
  uint4 u;
  u.x = (unsigned)h[0] | ((unsigned)h[1] << 16);
  u.y = (unsigned)h[2] | ((unsigned)h[3] << 16);
  u.z = (unsigned)h[4] | ((unsigned)h[5] << 16);
  u.w = (unsigned)h[6] | ((unsigned)h[7] << 16);
  return u;
}

// Tiled operand layout (MFMA-fragment-major):
//   frag(tile, kt) at [tile][kt][lane][8] u16, lane = quad*16+col,
//   element j = M[row=col][k = kt*32 + quad*8 + j]. Wave frag load = base + lane*16B.
// GEMM staging lesson (R5/R6/R7): global_load_lds deep rings stall at the LDS-DMA
// queue (R6: 2x SLOWER); register staging with compiler-counted vmcnt works --
// each lane's 16B global load IS its fragment. R7 period-3 took gemm1 below the
// knn line; this round deepens to period-4 (3 stages in flight).

// ---------------- K1 MEGA: independent front-end work co-scheduled ----------------
// grid 3456 x 256:
//   id <  2048 : knn 3-NN partials (dispatched FIRST: the long pole, VALU-bound)
//   id <  2176 : weight cast (w0,w1 -> fragment-major bf16)
//   id <  2432 : feat2 transpose -> feat2Tb[b][n2][c] bf16 (2 half-passes, 33KB LDS)
//   else       : feat1 transpose -> xcatT kt 0..3
// Transposes are memory-bound and fill pipes knn leaves idle (knn: HBM 4%).
// Shared LDS = 34KB -> 4 blocks/CU -> knn keeps 16 waves/CU (~50% occ, same as solo).
__global__ __launch_bounds__(256) void mega_kernel(
    const float* __restrict__ xyz1, const float* __restrict__ xyz2,
    float* __restrict__ pd, int* __restrict__ pi,
    const float* __restrict__ w0, const float* __restrict__ w1,
    u16* __restrict__ w0b, u16* __restrict__ w1b,
    const float* __restrict__ feat2, u16* __restrict__ feat2Tb,
    const float* __restrict__ feat1, u16* __restrict__ xcatT)
{
  __shared__ __align__(16) float smem[64*133];     // 34,048 B, aliased per branch
  int t = threadIdx.x;
  int id = blockIdx.x;
  if (id < 2048) {
    // ---- knn: one point/thread, 128 candidates (branchy insert: measured best) ----
    float4* sp = (float4*)smem;
    int xb = id & 15, b = (id >> 4) & 15, chunk = id >> 8;
    const float* p2 = xyz2 + ((size_t)b * N2_ + chunk * 128) * 3;
    if (t < 128) sp[t] = make_float4(p2[t*3], p2[t*3+1], p2[t*3+2], 0.f);
    __syncthreads();
    int i = xb * 256 + t;
    const float* p1 = xyz1 + ((size_t)b * N1_ + i) * 3;
    float x = p1[0], y = p1[1], z = p1[2];
    float d0 = 1e30f, d1 = 1e30f, d2 = 1e30f;
    int i0 = 0, i1 = 0, i2 = 0;
    int jb = chunk * 128;
    #pragma unroll 4
    for (int j = 0; j < 128; ++j) {
      float4 p = sp[j];                            // broadcast: conflict-free
      float dx = x - p.x, dy = y - p.y, dz = z - p.z;
      float d = dx*dx + dy*dy + dz*dz;
      if (d < d2) {                                // strict <: stable (earlier j wins ties)
        int jj = jb + j;
        if (d < d0)      { d2=d1; i2=i1; d1=d0; i1=i0; d0=d; i0=jj; }
        else if (d < d1) { d2=d1; i2=i1; d1=d;  i1=jj; }
        else             { d2=d;  i2=jj; }
      }
    }
    int o = chunk*65536 + b*4096 + i;
    pd[o] = d0; pd[o + 524288] = d1; pd[o + 1048576] = d2;
    pi[o] = i0; pi[o + 524288] = i1; pi[o + 1048576] = i2;
    return;
  }
  if (id < 2176) {                                 // ---- castw ----
    int item = (id - 2048) * 256 + t;              // 0..32767
    if (item < 12288) {                            // w0: 256 rows x 48 chunks
      int m = item / 48, kc = item % 48;
      const float* p = w0 + m * CIN_ + kc * 8;
      u16 h8[8];
      #pragma unroll
      for (int j = 0; j < 8; ++j) h8[j] = f2bf(p[j]);
      int mt = m >> 4, col = m & 15, kt = kc >> 2, quad = kc & 3;
      *(uint4*)(w0b + ((mt*12 + kt)*512 + (quad*16 + col)*8)) = pack8(h8);
    } else if (item < 16384) {                     // w1: 128 rows x 32 chunks
      int i2 = item - 12288;
      int m = i2 >> 5, kc = i2 & 31;
      const float* p = w1 + m * CM_ + kc * 8;
      u16 h8[8];
      #pragma unroll
      for (int j = 0; j < 8; ++j) h8[j] = f2bf(p[j]);
      int mt = m >> 4, col = m & 15, kt = kc >> 2, quad = kc & 3;
      *(uint4*)(w1b + ((mt*8 + kt)*512 + (quad*16 + col)*8)) = pack8(h8);
    }
    return;
  }
  if (id < 2432) {
    // ---- feat2 transpose, 2 half-passes of 128 channels (fits 33KB LDS) ----
    float (*sA2)[129] = (float(*)[129])smem;
    int idx = id - 2176;
    int b = idx >> 4, n0 = (idx & 15) * 64;
    #pragma unroll 1
    for (int h = 0; h < 2; ++h) {
      if (h) __syncthreads();                      // protect sA2 reuse
      #pragma unroll
      for (int j = 0; j < 8; ++j) {
        int flat4 = t + j * 256;                   // 2048 float4s: 128c x 64n
        int cl = flat4 >> 4, nn4 = (flat4 & 15) * 4;
        float4 v = *(const float4*)(feat2 + ((size_t)b*C2_ + h*128 + cl)*N2_ + n0 + nn4);
        sA2[nn4+0][cl] = v.x; sA2[nn4+1][cl] = v.y; sA2[nn4+2][cl] = v.z; sA2[nn4+3][cl] = v.w;
      }
      __syncthreads();
      int nn = t & 63, chunk = t >> 6;             // 4 x 32-channel groups per half
      u16* dst = feat2Tb + ((size_t)b*N2_ + n0 + nn)*C2_ + h*128 + chunk*32;
      #pragma unroll
      for (int g = 0; g < 4; ++g) {
        u16 h8[8];
        #pragma unroll
        for (int j = 0; j < 8; ++j) h8[j] = f2bf(sA2[nn][chunk*32 + g*8 + j]);
        *(uint4*)(dst + g*8) = pack8(h8);
      }
    }
    return;
  }
  {
    // ---- feat1 transpose -> xcatT kt 0..3 ----
    float (*sA1)[133] = (float(*)[133])smem;
    int idx = id - 2432;
    int b = idx >> 6, n0 = (idx & 63) * 64;
    #pragma unroll
    for (int j = 0; j < 8; ++j) {
      int flat4 = t + j * 256;                     // 2048 float4s: 128c x 64n
      int c = flat4 >> 4, nn4 = (flat4 & 15) * 4;
      float4 v = *(const float4*)(feat1 + ((size_t)b*C1_ + c)*N1_ + n0 + nn4);
      sA1[nn4+0][c] = v.x; sA1[nn4+1][c] = v.y; sA1[nn4+2][c] = v.z; sA1[nn4+3][c] = v.w;
    }
    __syncthreads();
    int nn = t & 63, chunk = t >> 6;
    int n = n0 + nn, nt = n >> 4, col = n & 15;
    u16* tb = xcatT + ((size_t)b*256 + nt)*12*512;
    #pragma unroll
    for (int g = 0; g < 4; ++g) {
      int c0 = chunk*32 + g*8;
      u16 h8[8];
      #pragma unroll
      for (int j = 0; j < 8; ++j) h8[j] = f2bf(sA1[nn][c0 + j]);
      *(uint4*)(tb + (size_t)chunk*512 + (g*16 + col)*8) = pack8(h8);
    }
  }
}

// ---------------- K2: merge 8 knn chunk-triples -> final idx/weights ----------------
__global__ __launch_bounds__(256) void merge_kernel(
    const float* __restrict__ pd, const int* __restrict__ pi,
    int* __restrict__ idx_out, float* __restrict__ w_out)
{
  int p = blockIdx.x * 256 + threadIdx.x;          // 0..65535
  float d0 = 1e30f, d1 = 1e30f, d2 = 1e30f;
  int i0 = 0, i1 = 0, i2 = 0;
  #pragma unroll
  for (int c = 0; c < 8; ++c) {                    // ascending-j chunk order: stable
    int o = c*65536 + p;
    #pragma unroll
    for (int k = 0; k < 3; ++k) {
      float d = pd[o + k*524288];
      int ix = pi[o + k*524288];
      bool c2 = d < d2, c1 = d < d1, c0 = d < d0;
      d2 = c1 ? d1 : (c2 ? d  : d2);
      i2 = c1 ? i1 : (c2 ? ix : i2);
      d1 = c0 ? d0 : (c1 ? d  : d1);
      i1 = c0 ? i0 : (c1 ? ix : i1);
      d0 = c0 ? d  : d0;
      i0 = c0 ? ix : i0;
    }
  }
  float w0 = 1.f/(d0+1e-8f), w1 = 1.f/(d1+1e-8f), w2 = 1.f/(d2+1e-8f);
  float inv = 1.f/(w0+w1+w2);
  idx_out[p]          = i0;
  idx_out[p +  65536] = i1;
  idx_out[p + 131072] = i2;
  w_out[p]            = w0*inv;
  w_out[p +  65536]   = w1*inv;
  w_out[p + 131072]   = w2*inv;
}

// ---------------- K3: 3NN interpolate (bf16 gather) -> xcatT kt 4..11 ----------------
__global__ __launch_bounds__(256) void interp_kernel(
    const u16* __restrict__ feat2Tb,
    const int* __restrict__ idx_in, const float* __restrict__ w_in,
    u16* __restrict__ xcatT)
{
  int b = blockIdx.y;
  int t = threadIdx.x;
  int p0 = blockIdx.x * 64;
  int seg = t & 31;                                // 8-channel segment
  int pl  = t >> 5;                                // 8 points per pass
  #pragma unroll 2
  for (int pass = 0; pass < 8; ++pass) {
    int n = p0 + pass*8 + pl;
    int base = b*N1_ + n;
    int i0 = idx_in[base], i1 = idx_in[base + 65536], i2 = idx_in[base + 131072];
    float w0 = w_in[base], w1 = w_in[base + 65536], w2 = w_in[base + 131072];
    const u16* fb = feat2Tb + (size_t)b*N2_*C2_ + seg*8;
    U128 a, c, d;
    a.u = *(const uint4*)(fb + (size_t)i0*C2_);
    c.u = *(const uint4*)(fb + (size_t)i1*C2_);
    d.u = *(const uint4*)(fb + (size_t)i2*C2_);
    u16 h8[8];
    #pragma unroll
    for (int j = 0; j < 8; ++j)
      h8[j] = f2bf(w0*bf2f(a.s[j]) + w1*bf2f(c.s[j]) + w2*bf2f(d.s[j]));
    int nt = n >> 4, col = n & 15;
    int kt = 4 + (seg >> 2), quad = seg & 3;
    *(uint4*)(xcatT + (((size_t)b*256 + nt)*12 + kt)*512 + (quad*16 + col)*8) = pack8(h8);
  }
}

// ---------------- K4: GEMM1 MFMA, register-staged period-4 (3 stages in flight) ----------------
// grid (32,16,2): x = 8-ntile block, y = batch, z = M half. 4 waves (2x2), wave
// tile 64x64. Compiler inserts counted vmcnt(24) before each MM (no drain-to-0).
__global__ __launch_bounds__(256) void gemm1_mfma(
    const u16* __restrict__ xcatT, const u16* __restrict__ w0b,
    const float* __restrict__ b0p, u16* __restrict__ y0T,
    float* __restrict__ p0)
{
  __shared__ float ps[4][64][2];                   // [wave][ch64][sum|sq]
  int t = threadIdx.x;
  int wave = t >> 6, lane = t & 63;
  int col = lane & 15, quad = lane >> 4;
  int wm = wave >> 1, wn = wave & 1;
  int b = blockIdx.y;
  int mtb = blockIdx.z*8 + wm*4;
  int ntb = blockIdx.x*8 + wn*4;

  const u16* ap = w0b + lane*8;
  const u16* bp = xcatT + ((size_t)(b*256 + ntb)*12)*512 + lane*8;

  floatx4 acc[4][4] = {};
  bf16x8 aA[4], aB[4], aC[4], aD[4], bA[4], bB[4], bC[4], bD[4];

#define G1_LDA(BUF, KT) { _Pragma("unroll") for (int i = 0; i < 4; ++i) \
    BUF[i] = ldfrag(ap + (size_t)((mtb+i)*12 + (KT))*512); }
#define G1_LDB(BUF, KT) { _Pragma("unroll") for (int i = 0; i < 4; ++i) \
    BUF[i] = ldfrag(bp + (size_t)(i*12 + (KT))*512); }
#define G1_MM(A_, B_) { _Pragma("unroll") for (int mt = 0; mt < 4; ++mt) \
    _Pragma("unroll") for (int nt = 0; nt < 4; ++nt) \
      acc[mt][nt] = __builtin_amdgcn_mfma_f32_16x16x32_bf16(A_[mt], B_[nt], acc[mt][nt], 0, 0, 0); }

  G1_LDA(aA,0);  G1_LDB(bA,0);
  G1_LDA(aB,1);  G1_LDB(bB,1);
  G1_LDA(aC,2);  G1_LDB(bC,2);
  G1_LDA(aD,3);  G1_LDB(bD,3);
  G1_MM(aA,bA);  G1_LDA(aA,4);  G1_LDB(bA,4);
  G1_MM(aB,bB);  G1_LDA(aB,5);  G1_LDB(bB,5);
  G1_MM(aC,bC);  G1_LDA(aC,6);  G1_LDB(bC,6);
  G1_MM(aD,bD);  G1_LDA(aD,7);  G1_LDB(bD,7);
  G1_MM(aA,bA);  G1_LDA(aA,8);  G1_LDB(bA,8);
  G1_MM(aB,bB);  G1_LDA(aB,9);  G1_LDB(bB,9);
  G1_MM(aC,bC);  G1_LDA(aC,10); G1_LDB(bC,10);
  G1_MM(aD,bD);  G1_LDA(aD,11); G1_LDB(bD,11);
  G1_MM(aA,bA);
  G1_MM(aB,bB);
  G1_MM(aC,bC);
  G1_MM(aD,bD);

  int m0 = blockIdx.z*128 + wm*64;
  #pragma unroll
  for (int mt = 0; mt < 4; ++mt) {
    float4 bias4 = *(const float4*)(b0p + m0 + mt*16 + quad*4);
    float bia[4] = {bias4.x, bias4.y, bias4.z, bias4.w};
    int kt_out = (m0 >> 5) + (mt >> 1);
    int quad_out = ((mt & 1) << 1) | (quad >> 1);
    int j0 = (quad & 1) * 4;
    float s[4] = {}, q[4] = {};
    #pragma unroll
    for (int nt = 0; nt < 4; ++nt) {
      int nt_g = ntb + nt;
      u16 h[4];
      #pragma unroll
      for (int r = 0; r < 4; ++r) {
        float v = acc[mt][nt][r] + bia[r];
        u16 hh = f2bf(v);
        float vr = bf2f(hh);
        h[r] = hh; s[r] += vr; q[r] += vr*vr;
      }
      *(ushort4*)(y0T + (((size_t)b*256 + nt_g)*8 + kt_out)*512 + (quad_out*16 + col)*8 + j0)
          = make_ushort4(h[0], h[1], h[2], h[3]);
    }
    #pragma unroll
    for (int r = 0; r < 4; ++r) {
      float ss = s[r], qq = q[r];
      #pragma unroll
      for (int msk = 1; msk < 16; msk <<= 1) { ss += __shfl_xor(ss, msk); qq += __shfl_xor(qq, msk); }
      if (col == 0) {
        ps[wave][mt*16 + quad*4 + r][0] = ss;
        ps[wave][mt*16 + quad*4 + r][1] = qq;
      }
    }
  }
  __syncthreads();
  {
    int c = t >> 1, k = t & 1;                     // c in [0,128)
    int wbase = (c >> 6) * 2, ch = c & 63;
    float v = ps[wbase][ch][k] + ps[wbase+1][ch][k];
    size_t l = (size_t)blockIdx.z*512 + blockIdx.y*32 + blockIdx.x;
    p0[l*256 + t] = v;
  }
}

// ---------------- K4.5: finalize stats -> scale/shift per channel ----------------
__global__ __launch_bounds__(256) void stats_kernel(
    const float* __restrict__ p, const float* __restrict__ g,
    const float* __restrict__ be, float* __restrict__ scale,
    float* __restrict__ shift, int half_split, int nl)
{
  int c = blockIdx.x, t = threadIdx.x;
  size_t base = half_split ? ((size_t)(c >> 7) * 512 * 256 + (size_t)(c & 127) * 2)
                           : ((size_t)c * 2);
  float s = 0.f, q = 0.f;
  for (int i = 0; i < nl; ++i) {
    float2 v = *(const float2*)(p + base + (size_t)(t + i*256) * 256);
    s += v.x; q += v.y;
  }
  #pragma unroll
  for (int m = 1; m < 64; m <<= 1) { s += __shfl_xor(s, m); q += __shfl_xor(q, m); }
  __shared__ float2 red[4];
  if ((t & 63) == 0) red[t >> 6] = make_float2(s, q);
  __syncthreads();
  if (t == 0) {
    float ss = red[0].x + red[1].x + red[2].x + red[3].x;
    float qq = red[0].y + red[1].y + red[2].y + red[3].y;
    float mu  = ss * (1.f/65536.f);
    float var = qq * (1.f/65536.f) - mu*mu;
    float a = g[c] * rsqrtf(var + 1e-5f);
    scale[c] = a; shift[c] = be[c] - mu*a;
  }
}

// ---------------- K5: GEMM2 MFMA, register-staged period-3, BN0+ReLU on B ----------------
// grid (32,16): 4 waves (2x2), wave tile 64x64, K=8 steps.
__global__ __launch_bounds__(256) void gemm2_mfma(
    const u16* __restrict__ y0T, const u16* __restrict__ w1b,
    const float* __restrict__ b1p,
    const float* __restrict__ scale0, const float* __restrict__ shift0,
    float* __restrict__ out, float* __restrict__ p1)
{
  __shared__ float a0s[CM_], bb0s[CM_];
  __shared__ float ps[4][64][2];
  int t = threadIdx.x;
  a0s[t] = scale0[t]; bb0s[t] = shift0[t];
  __syncthreads();
  int wave = t >> 6, lane = t & 63;
  int col = lane & 15, quad = lane >> 4;
  int wm = wave >> 1, wn = wave & 1;
  int b = blockIdx.y;
  int mtb = wm*4;
  int ntb = blockIdx.x*8 + wn*4;

  const u16* ap = w1b + lane*8;
  const u16* bp = y0T + ((size_t)(b*256 + ntb)*8)*512 + lane*8;

  floatx4 acc[4][4] = {};
  bf16x8 aA[4], aB[4], aC[4];
  U128 rA[4], rB[4], rC[4];

#define G2_LDA(BUF, KT) { _Pragma("unroll") for (int i = 0; i < 4; ++i) \
    BUF[i] = ldfrag(ap + (size_t)((mtb+i)*8 + (KT))*512); }
#define G2_LDB(BUF, KT) { _Pragma("unroll") for (int i = 0; i < 4; ++i) \
    BUF[i].u = *(const uint4*)(bp + (size_t)(i*8 + (KT))*512); }
#define G2_BNMM(A_, R_, KT) { \
    int c0 = (KT)*32 + quad*8; \
    float av[8], bv[8]; \
    *(float4*)&av[0] = *(const float4*)&a0s[c0];  *(float4*)&av[4] = *(const float4*)&a0s[c0+4]; \
    *(float4*)&bv[0] = *(const float4*)&bb0s[c0]; *(float4*)&bv[4] = *(const float4*)&bb0s[c0+4]; \
    bf16x8 bfv[4]; \
    _Pragma("unroll") for (int j = 0; j < 4; ++j) { \
      u16 h8[8]; \
      _Pragma("unroll") for (int e = 0; e < 8; ++e) \
        h8[e] = f2bf(fmaxf(fmaf(bf2f(R_[j].s[e]), av[e], bv[e]), 0.f)); \
      U128 x_; x_.u = pack8(h8); bfv[j] = x_.v; } \
    _Pragma("unroll") for (int mt = 0; mt < 4; ++mt) \
    _Pragma("unroll") for (int nt = 0; nt < 4; ++nt) \
      acc[mt][nt] = __builtin_amdgcn_mfma_f32_16x16x32_bf16(A_[mt], bfv[nt], acc[mt][nt], 0, 0, 0); }

  G2_LDA(aA,0);  G2_LDB(rA,0);
  G2_LDA(aB,1);  G2_LDB(rB,1);
  G2_LDA(aC,2);  G2_LDB(rC,2);
  G2_BNMM(aA,rA,0);  G2_LDA(aA,3);  G2_LDB(rA,3);
  G2_BNMM(aB,rB,1);  G2_LDA(aB,4);  G2_LDB(rB,4);
  G2_BNMM(aC,rC,2);  G2_LDA(aC,5);  G2_LDB(rC,5);
  G2_BNMM(aA,rA,3);  G2_LDA(aA,6);  G2_LDB(rA,6);
  G2_BNMM(aB,rB,4);  G2_LDA(aB,7);  G2_LDB(rB,7);
  G2_BNMM(aC,rC,5);
  G2_BNMM(aA,rA,6);
  G2_BNMM(aB,rB,7);

  int m0 = wm*64;
  int n0 = blockIdx.x*128 + wn*64;
  #pragma unroll
  for (int mt = 0; mt < 4; ++mt) {
    float4 bias4 = *(const float4*)(b1p + m0 + mt*16 + quad*4);
    float bia[4] = {bias4.x, bias4.y, bias4.z, bias4.w};
    float s[4] = {}, q[4] = {};
    #pragma unroll
    for (int nt = 0; nt < 4; ++nt) {
      int n = n0 + nt*16 + col;
      #pragma unroll
      for (int r = 0; r < 4; ++r) {
        float v = acc[mt][nt][r] + bia[r];
        out[((size_t)b*CO_ + m0 + mt*16 + quad*4 + r)*N1_ + n] = v;
        s[r] += v; q[r] += v*v;
      }
    }
    #pragma unroll
    for (int r = 0; r < 4; ++r) {
      float ss = s[r], qq = q[r];
      #pragma unroll
      for (int msk = 1; msk < 16; msk <<= 1) { ss += __shfl_xor(ss, msk); qq += __shfl_xor(qq, msk); }
      if (col == 0) {
        ps[wave][mt*16 + quad*4 + r][0] = ss;
        ps[wave][mt*16 + quad*4 + r][1] = qq;
      }
    }
  }
  __syncthreads();
  {
    int c = t >> 1, k = t & 1;
    int wbase = (c >> 6) * 2, ch = c & 63;
    float v = ps[wbase][ch][k] + ps[wbase+1][ch][k];
    size_t l = (size_t)blockIdx.y*32 + blockIdx.x;
    p1[l*256 + t] = v;
  }
}

// ---------------- K6: BN1 + ReLU in place on d_out ----------------
__global__ __launch_bounds__(256) void bnrelu_kernel(
    float* __restrict__ out, const float* __restrict__ scale1, const float* __restrict__ shift1)
{
  int idx = blockIdx.x * 256 + threadIdx.x;   // float4 index
  int c = (idx >> 10) & (CO_ - 1);
  float a = scale1[c];
  float bb = shift1[c];
  float4 v = ((const float4*)out)[idx];
  v.x = fmaxf(fmaf(v.x, a, bb), 0.f);
  v.y = fmaxf(fmaf(v.y, a, bb), 0.f);
  v.z = fmaxf(fmaf(v.z, a, bb), 0.f);
  v.w = fmaxf(fmaf(v.w, a, bb), 0.f);
  ((float4*)out)[idx] = v;
}

extern "C" void kernel_launch(void* const* d_in, const int* in_sizes, int n_in,
                              void* d_out, int out_size, void* d_ws, size_t ws_size,
                              hipStream_t stream)
{
  const float* xyz1  = (const float*)d_in[0];
  const float* xyz2  = (const float*)d_in[1];
  const float* feat1 = (const float*)d_in[2];
  const float* feat2 = (const float*)d_in[3];
  const float* w0    = (const float*)d_in[4];
  const float* b0    = (const float*)d_in[5];
  const float* g0    = (const float*)d_in[6];
  const float* be0   = (const float*)d_in[7];
  const float* w1    = (const float*)d_in[8];
  const float* b1    = (const float*)d_in[9];
  const float* g1    = (const float*)d_in[10];
  const float* be1   = (const float*)d_in[11];
  float* out = (float*)d_out;
  char* ws = (char*)d_ws;

  // workspace layout (bytes). NOTE: knn_pd/pi moved out of xcatT (f1-transpose now
  // writes xcatT kt0..3 concurrently with knn in K1) into the y0T region after
  // feat2Tb; both consumed before gemm1 writes y0T.
  u16*   xcatT   = (u16*)ws;                                   // 50331648
  float* p1      = (float*)ws;                                 // 524288 (alias xcatT; gemm2 writes after gemm1 consumed xcatT)
  u16*   y0T     = (u16*)(ws + 50331648);                      // 33554432
  u16*   feat2Tb = (u16*)(ws + 50331648);                      // 8388608 (alias y0T head)
  float* knn_pd  = (float*)(ws + 58720256);                    // 6291456 (alias y0T mid)
  int*   knn_pi  = (int*)(ws + 65011712);                      // 6291456 (alias y0T mid)
  u16*   w0b     = (u16*)(ws + 83886080);                      // 196608
  u16*   w1b     = (u16*)(ws + 84082688);                      // 65536
  int*   idx_buf = (int*)(ws + 84148224);                      // 786432
  float* w_buf   = (float*)(ws + 84934656);                    // 786432
  float* p0      = (float*)(ws + 85721088);                    // 1048576
  float* scale0  = (float*)(ws + 87293952);                    // 256
  float* shift0  = scale0 + 256;
  float* scale1  = scale0 + 512;
  float* shift1  = scale0 + 640;

  mega_kernel  <<<3456,           256, 0, stream>>>(xyz1, xyz2, knn_pd, knn_pi, w0, w1,
                                                    w0b, w1b, feat2, feat2Tb, feat1, xcatT);
  merge_kernel <<<256,            256, 0, stream>>>(knn_pd, knn_pi, idx_buf, w_buf);
  interp_kernel<<<dim3(64,16),    256, 0, stream>>>(feat2Tb, idx_buf, w_buf, xcatT);
  gemm1_mfma   <<<dim3(32,16,2),  256, 0, stream>>>(xcatT, w0b, b0, y0T, p0);
  stats_kernel <<<256,            256, 0, stream>>>(p0, g0, be0, scale0, shift0, 1, 2);
  gemm2_mfma   <<<dim3(32,16),    256, 0, stream>>>(y0T, w1b, b1, scale0, shift0, out, p1);
  stats_kernel <<<128,            256, 0, stream>>>(p1, g1, be1, scale1, shift1, 0, 2);
  bnrelu_kernel<<<8192,           256, 0, stream>>>(out, scale1, shift1);
}